// Round 2
// baseline (143.289 us; speedup 1.0000x reference)
//
#include <hip/hip_runtime.h>

#define FF 20
#define NI 190         // F*(F-1)/2
#define NIP 192        // padded
#define BB 4096
#define FD 320         // F*D
#define PV 20          // padded row stride (floats) for s_v: spreads banks, keeps 16B align

// K1: W12p[320][192] = senet_w1[320][320] @ senet_w2[320][190], zero-padded cols
__global__ __launch_bounds__(192) void k_w12(const float* __restrict__ w1,
                                             const float* __restrict__ w2,
                                             float* __restrict__ W12p) {
    __shared__ float srow[FD];
    int r = blockIdx.x;
    for (int j = threadIdx.x; j < FD; j += 192) srow[j] = w1[r * FD + j];
    __syncthreads();
    int c = threadIdx.x;   // 0..191
    float acc = 0.f;
    if (c < NI) {
        for (int k = 0; k < FD; ++k) acc += srow[k] * w2[k * NI + c];
    }
    W12p[r * NIP + c] = acc;
}

// K2: w[4096][192] = z[4096][320] @ W12p[320][192]. 64x64 tiles, 4x4 per thread.
__global__ __launch_bounds__(256) void k_w(const float* __restrict__ z,
                                           const float* __restrict__ W12p,
                                           float* __restrict__ wout) {
    __shared__ float zT[32][68];
    __shared__ float Ws[32][64];
    int b0 = blockIdx.x * 64;
    int c0 = blockIdx.y * 64;
    int t = threadIdx.x;
    int tr = t >> 4, tc = t & 15;
    float acc[4][4];
#pragma unroll
    for (int i = 0; i < 4; ++i)
#pragma unroll
        for (int j = 0; j < 4; ++j) acc[i][j] = 0.f;

    for (int k0 = 0; k0 < FD; k0 += 32) {
#pragma unroll
        for (int s = 0; s < 2; ++s) {
            int task = t + s * 256;
            int row = task >> 3, ch = task & 7;
            float4 v = *(const float4*)&z[(b0 + row) * FD + k0 + ch * 4];
            zT[ch * 4 + 0][row] = v.x;
            zT[ch * 4 + 1][row] = v.y;
            zT[ch * 4 + 2][row] = v.z;
            zT[ch * 4 + 3][row] = v.w;
        }
#pragma unroll
        for (int s = 0; s < 2; ++s) {
            int task = t + s * 256;
            int kr = task >> 4, cq = task & 15;
            *(float4*)&Ws[kr][cq * 4] = *(const float4*)&W12p[(k0 + kr) * NIP + c0 + cq * 4];
        }
        __syncthreads();
#pragma unroll
        for (int k = 0; k < 32; ++k) {
            float4 zb = *(const float4*)&zT[k][tr * 4];
            float4 wv = *(const float4*)&Ws[k][tc * 4];
            float zz[4] = {zb.x, zb.y, zb.z, zb.w};
            float ww[4] = {wv.x, wv.y, wv.z, wv.w};
#pragma unroll
            for (int i = 0; i < 4; ++i)
#pragma unroll
                for (int j = 0; j < 4; ++j) acc[i][j] += zz[i] * ww[j];
        }
        __syncthreads();
    }
#pragma unroll
    for (int i = 0; i < 4; ++i) {
        float4 v = make_float4(acc[i][0], acc[i][1], acc[i][2], acc[i][3]);
        *(float4*)&wout[(b0 + tr * 4 + i) * NIP + c0 + tc * 4] = v;
    }
}

// K3: pair-major stage-once formulation.
// Phase A (per hash): v[p][0:16] = w[p] * cb[idx_h[p]]  -- each row gathered ONCE
//   (380 row-gathers/block instead of 760; float4 lanes -> 4x fewer VMEM insts).
// Phase B (per hash): acc_h[f][d] = sum_{j in pairs(f)} v[pl[f][j]][d]  (LDS only).
// Hash1 gathers are issued into registers during hash0's Phase B (async split).
// Then out[b,f,:] = acc0 @ W[0:16] + acc1 @ W[16:32] via s_acc staging.
// LDS ~24 KB -> 6 blocks/CU (wave-limited, 30 waves/CU).
#define SA(f, h, d) ((f) * 33 + (h) * 16 + (d))
__global__ __launch_bounds__(320) void k_main(const float* __restrict__ cb,   // [500000][16]
                                              const float* __restrict__ Wt,   // [32][16]
                                              const int* __restrict__ hidx,   // [2][B][NI]
                                              const int* __restrict__ iidx,   // [20][19]
                                              const float* __restrict__ wbuf, // [B][192]
                                              float* __restrict__ out) {      // [B][20][16]
    __shared__ int s_i0[NI], s_i1[NI];
    __shared__ float s_w[NI];
    __shared__ int s_plist[FF * 19];
    __shared__ float s_W[32 * 16];
    __shared__ __align__(16) float s_v[NI * PV];
    __shared__ float s_acc[19 * 33 + 2 * 16 + 16];

    int t = threadIdx.x;
    int b = blockIdx.x;

    if (t < NI) {
        s_i0[t] = hidx[b * NI + t];
        s_i1[t] = hidx[(BB + b) * NI + t];
        s_w[t] = wbuf[b * NIP + t];
    }
    for (int j = t; j < FF * 19; j += 320) s_plist[j] = iidx[j];
    for (int j = t; j < 512; j += 320) s_W[j] = Wt[j];
    __syncthreads();

    const float4* cb4 = (const float4*)cb;
    int q  = t & 3;    // quad within a 16-float row
    int pb = t >> 2;   // 0..79  (pair base; pairs pb, pb+80, pb+160)
    bool has3 = pb < (NI - 160);   // pb < 30

    // ---- Phase A0: gather hash0 rows (x w) ----
    float4 g0a = cb4[s_i0[pb] * 4 + q];
    float4 g0b = cb4[s_i0[pb + 80] * 4 + q];
    float4 g0c;
    if (has3) g0c = cb4[s_i0[pb + 160] * 4 + q];
    float w_a = s_w[pb], w_b = s_w[pb + 80];
    float w_c = has3 ? s_w[pb + 160] : 0.f;

    *(float4*)&s_v[pb * PV + q * 4] =
        make_float4(g0a.x * w_a, g0a.y * w_a, g0a.z * w_a, g0a.w * w_a);
    *(float4*)&s_v[(pb + 80) * PV + q * 4] =
        make_float4(g0b.x * w_b, g0b.y * w_b, g0b.z * w_b, g0b.w * w_b);
    if (has3)
        *(float4*)&s_v[(pb + 160) * PV + q * 4] =
            make_float4(g0c.x * w_c, g0c.y * w_c, g0c.z * w_c, g0c.w * w_c);
    __syncthreads();

    // ---- Issue hash1 gathers now; they fly under Phase B0's LDS work ----
    float4 g1a = cb4[s_i1[pb] * 4 + q];
    float4 g1b = cb4[s_i1[pb + 80] * 4 + q];
    float4 g1c;
    if (has3) g1c = cb4[s_i1[pb + 160] * 4 + q];

    // ---- Phase B0: per-field accumulate from LDS ----
    int f = t >> 4, d = t & 15;
    const int* pl = &s_plist[f * 19];
    float a0 = 0.f;
#pragma unroll
    for (int j = 0; j < 19; ++j) a0 += s_v[pl[j] * PV + d];
    __syncthreads();   // B0 reads done before s_v overwrite

    *(float4*)&s_v[pb * PV + q * 4] =
        make_float4(g1a.x * w_a, g1a.y * w_a, g1a.z * w_a, g1a.w * w_a);
    *(float4*)&s_v[(pb + 80) * PV + q * 4] =
        make_float4(g1b.x * w_b, g1b.y * w_b, g1b.z * w_b, g1b.w * w_b);
    if (has3)
        *(float4*)&s_v[(pb + 160) * PV + q * 4] =
            make_float4(g1c.x * w_c, g1c.y * w_c, g1c.z * w_c, g1c.w * w_c);
    __syncthreads();

    // ---- Phase B1 ----
    float a1 = 0.f;
#pragma unroll
    for (int j = 0; j < 19; ++j) a1 += s_v[pl[j] * PV + d];

    s_acc[SA(f, 0, d)] = a0;
    s_acc[SA(f, 1, d)] = a1;
    __syncthreads();

    // ---- Transform: out[b,f,d] = sum_k acc0[f][k]*W[k][d] + acc1[f][k]*W[16+k][d]
    float r = 0.f;
#pragma unroll
    for (int k = 0; k < 16; ++k) {
        r += s_acc[SA(f, 0, k)] * s_W[k * 16 + d];
        r += s_acc[SA(f, 1, k)] * s_W[(16 + k) * 16 + d];
    }
    out[b * FD + t] = r;
}

extern "C" void kernel_launch(void* const* d_in, const int* in_sizes, int n_in,
                              void* d_out, int out_size, void* d_ws, size_t ws_size,
                              hipStream_t stream) {
    const float* origin = (const float*)d_in[0];  // (B, F, D) = z
    const float* cb     = (const float*)d_in[1];  // (500000, 16)
    const float* Wt     = (const float*)d_in[2];  // (32, 16)
    const float* w1     = (const float*)d_in[3];  // (320, 320)
    const float* w2     = (const float*)d_in[4];  // (320, 190)
    const int*   hidx   = (const int*)d_in[5];    // (2, B, 190)
    const int*   iidx   = (const int*)d_in[6];    // (20, 19)
    float* out = (float*)d_out;

    float* W12p = (float*)d_ws;           // 320*192 floats
    float* wbuf = W12p + FD * NIP;        // 4096*192 floats

    k_w12<<<FD, 192, 0, stream>>>(w1, w2, W12p);
    dim3 gw(BB / 64, 3);
    k_w<<<gw, 256, 0, stream>>>(origin, W12p, wbuf);
    k_main<<<BB, 320, 0, stream>>>(cb, Wt, hidx, iidx, wbuf, out);
}